// Round 7
// baseline (282.411 us; speedup 1.0000x reference)
//
#include <hip/hip_runtime.h>
#include <math.h>

#define SPAT  96
#define IMG   (SPAT*SPAT)        /* 9216    */
#define PLANE (SPAT*SPAT*SPAT)   /* 884736  */
#define DPB   8                  /* d-planes per block */
#define NRI   (DPB*SPAT)         /* rowinfo entries per block: 768 */

typedef float f32x4 __attribute__((ext_vector_type(4)));

// ---------------------------------------------------------------------------
// 4x4 matrix inverse (adjugate)
// ---------------------------------------------------------------------------
__device__ inline void invert4(const float m[16], float inv[16]) {
    inv[0]  =  m[5]*m[10]*m[15] - m[5]*m[11]*m[14] - m[9]*m[6]*m[15] + m[9]*m[7]*m[14] + m[13]*m[6]*m[11] - m[13]*m[7]*m[10];
    inv[4]  = -m[4]*m[10]*m[15] + m[4]*m[11]*m[14] + m[8]*m[6]*m[15] - m[8]*m[7]*m[14] - m[12]*m[6]*m[11] + m[12]*m[7]*m[10];
    inv[8]  =  m[4]*m[9]*m[15]  - m[4]*m[11]*m[13] - m[8]*m[5]*m[15] + m[8]*m[7]*m[13] + m[12]*m[5]*m[11] - m[12]*m[7]*m[9];
    inv[12] = -m[4]*m[9]*m[14]  + m[4]*m[10]*m[13] + m[8]*m[5]*m[14] - m[8]*m[6]*m[13] - m[12]*m[5]*m[10] + m[12]*m[6]*m[9];
    inv[1]  = -m[1]*m[10]*m[15] + m[1]*m[11]*m[14] + m[9]*m[2]*m[15] - m[9]*m[3]*m[14] - m[13]*m[2]*m[11] + m[13]*m[3]*m[10];
    inv[5]  =  m[0]*m[10]*m[15] - m[0]*m[11]*m[14] - m[8]*m[2]*m[15] + m[8]*m[3]*m[14] + m[12]*m[2]*m[11] - m[12]*m[3]*m[10];
    inv[9]  = -m[0]*m[9]*m[15]  + m[0]*m[11]*m[13] + m[8]*m[1]*m[15] - m[8]*m[3]*m[13] - m[12]*m[1]*m[11] + m[12]*m[3]*m[9];
    inv[13] =  m[0]*m[9]*m[14]  - m[0]*m[10]*m[13] - m[8]*m[1]*m[14] + m[8]*m[2]*m[13] + m[12]*m[1]*m[10] - m[12]*m[2]*m[9];
    inv[2]  =  m[1]*m[6]*m[15]  - m[1]*m[7]*m[14]  - m[5]*m[2]*m[15] + m[5]*m[3]*m[14] + m[13]*m[2]*m[7]  - m[13]*m[3]*m[6];
    inv[6]  = -m[0]*m[6]*m[15]  + m[0]*m[7]*m[14]  + m[4]*m[2]*m[15] - m[4]*m[3]*m[14] - m[12]*m[2]*m[7]  + m[12]*m[3]*m[6];
    inv[10] =  m[0]*m[5]*m[15]  - m[0]*m[7]*m[13]  - m[4]*m[1]*m[15] + m[4]*m[3]*m[13] + m[12]*m[1]*m[7]  - m[12]*m[3]*m[5];
    inv[14] = -m[0]*m[5]*m[14]  + m[0]*m[6]*m[13]  + m[4]*m[1]*m[14] - m[4]*m[2]*m[13] - m[12]*m[1]*m[6]  + m[12]*m[2]*m[5];
    inv[3]  = -m[1]*m[6]*m[11]  + m[1]*m[7]*m[10]  + m[5]*m[2]*m[11] - m[5]*m[3]*m[10] - m[9]*m[2]*m[7]   + m[9]*m[3]*m[6];
    inv[7]  =  m[0]*m[6]*m[11]  - m[0]*m[7]*m[10]  - m[4]*m[2]*m[11] + m[4]*m[3]*m[10] + m[8]*m[2]*m[7]   - m[8]*m[3]*m[6];
    inv[11] = -m[0]*m[5]*m[11]  + m[0]*m[7]*m[9]   + m[4]*m[1]*m[11] - m[4]*m[3]*m[9]  - m[8]*m[1]*m[7]   + m[8]*m[3]*m[5];
    inv[15] =  m[0]*m[5]*m[10]  - m[0]*m[6]*m[9]   - m[4]*m[1]*m[10] + m[4]*m[2]*m[9]  + m[8]*m[1]*m[6]   - m[8]*m[2]*m[5];
    float det  = m[0]*inv[0] + m[1]*inv[4] + m[2]*inv[8] + m[3]*inv[12];
    float rdet = 1.0f / det;
    for (int i = 0; i < 16; ++i) inv[i] *= rdet;
}

__device__ inline void fold_affine(const float* __restrict__ aff_in, int sb,
                                   float M[12]) {
    float A[16];
    #pragma unroll
    for (int i = 0; i < 16; ++i) A[i] = aff_in[sb * 16 + i];
    #pragma unroll
    for (int j = 0; j < 3; ++j) {        // column-normalize by zooms
        float z = sqrtf(A[0*4+j]*A[0*4+j] + A[1*4+j]*A[1*4+j] + A[2*4+j]*A[2*4+j]);
        float rz = 1.0f / z;
        #pragma unroll
        for (int i = 0; i < 4; ++i) A[i*4+j] *= rz;
    }
    float inv[16];
    invert4(A, inv);
    #pragma unroll
    for (int r = 0; r < 3; ++r) {
        float T0 = inv[r*4+0], T1 = inv[r*4+1], T2 = inv[r*4+2], T3 = inv[r*4+3];
        // i_r = T0*w + T1*h + T2*d + [-47.5*(T0+T1+T2) + 48*T3 + 47.5]
        M[r*4+0] = T0;
        M[r*4+1] = T1;
        M[r*4+2] = T2;
        M[r*4+3] = -47.5f * (T0 + T1 + T2) + 48.0f * T3 + 47.5f;
    }
}

// ---------------------------------------------------------------------------
// fused5: block = (cc, 8 d-planes). Single kernel, single barrier.
//  Prologue: stage channel image (36 KB) in LDS (coalesced float4) + compute
//  all 768 row intervals into LDS (one rcp per row, amortized over 24
//  chunks). ONE __syncthreads.
//  Hot loop (8 planes x 9 iters/thread): static (h,q); ds_read rowinfo;
//  compare; rare slab body reads its 16 taps from LDS (no VMEM); every
//  chunk gets exactly one unconditional NONTEMPORAL float4 store.
//  Zero VMEM loads and zero barriers in the hot loop; stores coalesced.
//  LDS 39 KB -> 3 blocks/CU (12 waves).
// ---------------------------------------------------------------------------
__global__ __launch_bounds__(256) void fused5_kernel(
        const float* __restrict__ xin,   // [2,32,96,96]
        const float* __restrict__ aff_in,// [2,2,4,4]
        float* __restrict__ out) {       // [2,32,96,96,96]
    __shared__ float    simg[IMG];       // 36864 B
    __shared__ unsigned rinf[NRI];       // 3072 B
    const int tid  = (int)threadIdx.x;
    const int cc   = blockIdx.x;         // 0..63 = b*32 + s*16 + ct
    const int d0   = (int)blockIdx.y * DPB;
    const int b    = cc >> 5;
    const int s    = (cc >> 4) & 1;
    const int sb   = s * 2 + b;

    // ---- fold affine: every thread, registers (ILP-parallel) ----
    float M[12];
    fold_affine(aff_in, sb, M);
    const float Mxw = M[0], Mxh = M[1], Mxd = M[2],  Mx0 = M[3];
    const float Myw = M[4], Myh = M[5], Myd = M[6],  My0 = M[7];
    const float Mzw = M[8], Mzh = M[9], Mzd = M[10], Mz0 = M[11];

    // ---- stage channel image into LDS (coalesced float4) ----
    const f32x4* ip = reinterpret_cast<const f32x4*>(xin + (size_t)cc * IMG);
    f32x4* sp = reinterpret_cast<f32x4*>(simg);
    #pragma unroll
    for (int i = 0; i < IMG / 4 / 256; ++i)      // 9 iterations
        sp[tid + 256 * i] = ip[tid + 256 * i];

    // ---- row intervals for all DPB planes (one rcp per row) ----
    for (int r = tid; r < NRI; r += 256) {
        const int dp = r / SPAT;
        const int h  = r - dp * SPAT;
        const float fh = (float)h, fd = (float)(d0 + dp);
        const float bx = Mxh * fh + Mxd * fd + Mx0;
        int wlo, whi;
        if (fabsf(Mxw) > 1e-6f) {
            float rMxw = 1.0f / Mxw;
            float w1 = (47.0f - bx) * rMxw;
            float w2 = (49.0f - bx) * rMxw;
            float wmin = fminf(w1, w2), wmax = fmaxf(w1, w2);
            wlo = max((int)ceilf(wmin), 0);
            whi = min((int)floorf(wmax), SPAT - 1);
        } else {
            bool in = fabsf(bx - 48.0f) < 1.0f;
            wlo = in ? 0 : 1;
            whi = in ? SPAT - 1 : 0;
        }
        rinf[r] = (wlo > whi) ? 0xFFu
                : ((unsigned)(wlo >> 2) | ((unsigned)(whi >> 2) << 8));
    }

    __syncthreads();     // only barrier in the kernel

    // ---- static per-thread chunk coordinates (d-independent) ----
    int hh[9], qq[9];
    #pragma unroll
    for (int it = 0; it < 9; ++it) {
        const int tl = tid + 256 * it;           // 0..2303
        hh[it] = tl / 24;
        qq[it] = tl - hh[it] * 24;
    }

    // ---- hot loop: pure store stream + LDS-served rare slab body ----
    for (int dp = 0; dp < DPB; ++dp) {
        const float fd  = (float)(d0 + dp);
        const float bxd = Mxd * fd + Mx0;
        const float byd = Myd * fd + My0;
        const float bzd = Mzd * fd + Mz0;
        f32x4* op = reinterpret_cast<f32x4*>(out
            + (size_t)cc * PLANE + (size_t)(d0 + dp) * IMG);
        #pragma unroll
        for (int it = 0; it < 9; ++it) {
            const int h = hh[it], q = qq[it];
            const unsigned info = rinf[dp * SPAT + h];
            const bool ins = ((unsigned)q >= (info & 0xFFu))
                           & ((unsigned)q <= ((info >> 8) & 0xFFu));
            f32x4 v = {0.f, 0.f, 0.f, 0.f};
            if (ins) {
                const float fh = (float)h;
                const float bx = Mxh * fh + bxd;
                const float by = Myh * fh + byd;
                const float bz = Mzh * fh + bzd;
                #pragma unroll
                for (int j = 0; j < 4; ++j) {
                    float fw = (float)(4 * q + j);
                    float ix = Mxw * fw + bx;
                    float wx = 1.0f - fabsf(ix - 48.0f);
                    float r = 0.0f;
                    if (wx > 0.0f) {
                        float iy = Myw * fw + by;
                        float iz = Mzw * fw + bz;
                        float yf = floorf(iy), zf = floorf(iz);
                        float fy = iy - yf,    fz = iz - zf;
                        int y0 = (int)yf, z0 = (int)zf;
                        bool vy0 = (y0 >= 0)  & (y0 <  SPAT);
                        bool vy1 = (y0 >= -1) & (y0 <  SPAT - 1);
                        bool vz0 = (z0 >= 0)  & (z0 <  SPAT);
                        bool vz1 = (z0 >= -1) & (z0 <  SPAT - 1);
                        int y0c = min(max(y0, 0),     SPAT - 1);
                        int y1c = min(max(y0 + 1, 0), SPAT - 1);
                        int z0c = min(max(z0, 0),     SPAT - 1);
                        int z1c = min(max(z0 + 1, 0), SPAT - 1);
                        float wy0 = 1.0f - fy, wy1 = fy;
                        float wz0 = 1.0f - fz, wz1 = fz;
                        float w00 = wx * wz0 * wy0 * ((vz0 & vy0) ? 1.0f : 0.0f);
                        float w01 = wx * wz0 * wy1 * ((vz0 & vy1) ? 1.0f : 0.0f);
                        float w10 = wx * wz1 * wy0 * ((vz1 & vy0) ? 1.0f : 0.0f);
                        float w11 = wx * wz1 * wy1 * ((vz1 & vy1) ? 1.0f : 0.0f);
                        r = w00 * simg[z0c * SPAT + y0c]
                          + w01 * simg[z0c * SPAT + y1c]
                          + w10 * simg[z1c * SPAT + y0c]
                          + w11 * simg[z1c * SPAT + y1c];
                    }
                    v[j] = r;
                }
            }
            // streaming store: output is write-once, never re-read
            __builtin_nontemporal_store(v, op + (tid + 256 * it));
        }
    }
}

extern "C" void kernel_launch(void* const* d_in, const int* in_sizes, int n_in,
                              void* d_out, int out_size, void* d_ws, size_t ws_size,
                              hipStream_t stream) {
    const float* x   = (const float*)d_in[0];   // [2,32,96,96] fp32
    const float* aff = (const float*)d_in[1];   // [2,2,4,4]    fp32
    float* out = (float*)d_out;                 // [2,32,96,96,96] fp32

    dim3 grid(64, SPAT / DPB);                  // (cc, d-octant) = 768 blocks
    fused5_kernel<<<grid, 256, 0, stream>>>(x, aff, out);
}

// Round 8
// 221.375 us; speedup vs baseline: 1.2757x; 1.2757x over previous
//
#include <hip/hip_runtime.h>
#include <math.h>

#define SPAT  96
#define IMG   (SPAT*SPAT)        /* 9216   */
#define PLANE (SPAT*SPAT*SPAT)   /* 884736 */
#define KSLOT 3

typedef float f32x4 __attribute__((ext_vector_type(4)));

// ---------------------------------------------------------------------------
// 4x4 matrix inverse (adjugate)
// ---------------------------------------------------------------------------
__device__ inline void invert4(const float m[16], float inv[16]) {
    inv[0]  =  m[5]*m[10]*m[15] - m[5]*m[11]*m[14] - m[9]*m[6]*m[15] + m[9]*m[7]*m[14] + m[13]*m[6]*m[11] - m[13]*m[7]*m[10];
    inv[4]  = -m[4]*m[10]*m[15] + m[4]*m[11]*m[14] + m[8]*m[6]*m[15] - m[8]*m[7]*m[14] - m[12]*m[6]*m[11] + m[12]*m[7]*m[10];
    inv[8]  =  m[4]*m[9]*m[15]  - m[4]*m[11]*m[13] - m[8]*m[5]*m[15] + m[8]*m[7]*m[13] + m[12]*m[5]*m[11] - m[12]*m[7]*m[9];
    inv[12] = -m[4]*m[9]*m[14]  + m[4]*m[10]*m[13] + m[8]*m[5]*m[14] - m[8]*m[6]*m[13] - m[12]*m[5]*m[10] + m[12]*m[6]*m[9];
    inv[1]  = -m[1]*m[10]*m[15] + m[1]*m[11]*m[14] + m[9]*m[2]*m[15] - m[9]*m[3]*m[14] - m[13]*m[2]*m[11] + m[13]*m[3]*m[10];
    inv[5]  =  m[0]*m[10]*m[15] - m[0]*m[11]*m[14] - m[8]*m[2]*m[15] + m[8]*m[3]*m[14] + m[12]*m[2]*m[11] - m[12]*m[3]*m[10];
    inv[9]  = -m[0]*m[9]*m[15]  + m[0]*m[11]*m[13] + m[8]*m[1]*m[15] - m[8]*m[3]*m[13] - m[12]*m[1]*m[11] + m[12]*m[3]*m[9];
    inv[13] =  m[0]*m[9]*m[14]  - m[0]*m[10]*m[13] - m[8]*m[1]*m[14] + m[8]*m[2]*m[13] + m[12]*m[1]*m[10] - m[12]*m[2]*m[9];
    inv[2]  =  m[1]*m[6]*m[15]  - m[1]*m[7]*m[14]  - m[5]*m[2]*m[15] + m[5]*m[3]*m[14] + m[13]*m[2]*m[7]  - m[13]*m[3]*m[6];
    inv[6]  = -m[0]*m[6]*m[15]  + m[0]*m[7]*m[14]  + m[4]*m[2]*m[15] - m[4]*m[3]*m[14] - m[12]*m[2]*m[7]  + m[12]*m[3]*m[6];
    inv[10] =  m[0]*m[5]*m[15]  - m[0]*m[7]*m[13]  - m[4]*m[1]*m[15] + m[4]*m[3]*m[13] + m[12]*m[1]*m[7]  - m[12]*m[3]*m[5];
    inv[14] = -m[0]*m[5]*m[14]  + m[0]*m[6]*m[13]  + m[4]*m[1]*m[14] - m[4]*m[2]*m[13] - m[12]*m[1]*m[6]  + m[12]*m[2]*m[5];
    inv[3]  = -m[1]*m[6]*m[11]  + m[1]*m[7]*m[10]  + m[5]*m[2]*m[11] - m[5]*m[3]*m[10] - m[9]*m[2]*m[7]   + m[9]*m[3]*m[6];
    inv[7]  =  m[0]*m[6]*m[11]  - m[0]*m[7]*m[10]  - m[4]*m[2]*m[11] + m[4]*m[3]*m[10] + m[8]*m[2]*m[7]   - m[8]*m[3]*m[6];
    inv[11] = -m[0]*m[5]*m[11]  + m[0]*m[7]*m[9]   + m[4]*m[1]*m[11] - m[4]*m[3]*m[9]  - m[8]*m[1]*m[7]   + m[8]*m[3]*m[5];
    inv[15] =  m[0]*m[5]*m[10]  - m[0]*m[6]*m[9]   - m[4]*m[1]*m[10] + m[4]*m[2]*m[9]  + m[8]*m[1]*m[6]   - m[8]*m[2]*m[5];
    float det  = m[0]*inv[0] + m[1]*inv[4] + m[2]*inv[8] + m[3]*inv[12];
    float rdet = 1.0f / det;
    for (int i = 0; i < 16; ++i) inv[i] *= rdet;
}

__device__ inline void fold_affine(const float* __restrict__ aff_in, int sb,
                                   float M[12]) {
    float A[16];
    #pragma unroll
    for (int i = 0; i < 16; ++i) A[i] = aff_in[sb * 16 + i];
    #pragma unroll
    for (int j = 0; j < 3; ++j) {        // column-normalize by zooms
        float z = sqrtf(A[0*4+j]*A[0*4+j] + A[1*4+j]*A[1*4+j] + A[2*4+j]*A[2*4+j]);
        float rz = 1.0f / z;
        #pragma unroll
        for (int i = 0; i < 4; ++i) A[i*4+j] *= rz;
    }
    float inv[16];
    invert4(A, inv);
    #pragma unroll
    for (int r = 0; r < 3; ++r) {
        float T0 = inv[r*4+0], T1 = inv[r*4+1], T2 = inv[r*4+2], T3 = inv[r*4+3];
        // i_r = T0*w + T1*h + T2*d + [-47.5*(T0+T1+T2) + 48*T3 + 47.5]
        M[r*4+0] = T0;
        M[r*4+1] = T1;
        M[r*4+2] = T2;
        M[r*4+3] = -47.5f * (T0 + T1 + T2) + 48.0f * T3 + 47.5f;
    }
}

// trilinear-composed float4 chunk (4 w-voxels) from the L2-resident image
__device__ inline f32x4 compose_chunk(int q, float bx, float by, float bz,
        float Mxw, float Myw, float Mzw, const float* __restrict__ img) {
    f32x4 v;
    #pragma unroll
    for (int j = 0; j < 4; ++j) {
        float fw = (float)(4 * q + j);
        float ix = Mxw * fw + bx;
        float wx = 1.0f - fabsf(ix - 48.0f);
        float r = 0.0f;
        if (wx > 0.0f) {
            float iy = Myw * fw + by;
            float iz = Mzw * fw + bz;
            float yf = floorf(iy), zf = floorf(iz);
            float fy = iy - yf,    fz = iz - zf;
            int y0 = (int)yf, z0 = (int)zf;
            bool vy0 = (y0 >= 0)  & (y0 <  SPAT);
            bool vy1 = (y0 >= -1) & (y0 <  SPAT - 1);
            bool vz0 = (z0 >= 0)  & (z0 <  SPAT);
            bool vz1 = (z0 >= -1) & (z0 <  SPAT - 1);
            int y0c = min(max(y0, 0),     SPAT - 1);
            int y1c = min(max(y0 + 1, 0), SPAT - 1);
            int z0c = min(max(z0, 0),     SPAT - 1);
            int z1c = min(max(z0 + 1, 0), SPAT - 1);
            float wy0 = 1.0f - fy, wy1 = fy;
            float wz0 = 1.0f - fz, wz1 = fz;
            float w00 = wx * wz0 * wy0 * ((vz0 & vy0) ? 1.0f : 0.0f);
            float w01 = wx * wz0 * wy1 * ((vz0 & vy1) ? 1.0f : 0.0f);
            float w10 = wx * wz1 * wy0 * ((vz1 & vy0) ? 1.0f : 0.0f);
            float w11 = wx * wz1 * wy1 * ((vz1 & vy1) ? 1.0f : 0.0f);
            r = w00 * img[z0c * SPAT + y0c] + w01 * img[z0c * SPAT + y1c]
              + w10 * img[z1c * SPAT + y0c] + w11 * img[z1c * SPAT + y1c];
        }
        v[j] = r;
    }
    return v;
}

// ---------------------------------------------------------------------------
// fused6: block = (d, cc). Samplers (tid<192, 2 threads/row) compose the
// <=KSLOT slab chunks per h-row into sval[96x3] (4.6 KB) + rinf[96]; no
// tile zero, no tile copy, ONE barrier. Stream: 9 iterations of
// {2 broadcast LDS reads, compare, 4 cndmask, unconditional float4 store}
// -- zero VMEM loads, zero branches. LDS 5 KB + launch_bounds(256,8)
// (<=64 VGPR) => 8 blocks/CU, 32 waves/CU: sampler gather latency hides
// under other blocks' store streams. Pathological wide intervals (never
// for near-identity affines) are stored directly by samplers; stream skips.
// ---------------------------------------------------------------------------
__global__ __launch_bounds__(256, 8) void fused6_kernel(
        const float* __restrict__ xin,   // [2,32,96,96]
        const float* __restrict__ aff_in,// [2,2,4,4]
        f32x4* __restrict__ out) {       // [2,32,96,96,96] as float4 chunks
    __shared__ f32x4    sval[SPAT * KSLOT];  // 4608 B
    __shared__ unsigned rinf[SPAT];          // 384 B
    const int tid = (int)threadIdx.x;
    const int d   = blockIdx.x;          // 0..95
    const int cc  = blockIdx.y;          // 0..63 = b*32 + s*16 + ct
    const int b   = cc >> 5;
    const int s   = (cc >> 4) & 1;
    const int sb  = s * 2 + b;

    // ---- samplers: 2 threads per h-row (waves 0-2); wave 3 skips ----
    if (tid < 2 * SPAT) {
        float M[12];
        fold_affine(aff_in, sb, M);
        const float Mxw = M[0], Mxh = M[1], Mxd = M[2],  Mx0 = M[3];
        const float Myw = M[4], Myh = M[5], Myd = M[6],  My0 = M[7];
        const float Mzw = M[8], Mzh = M[9], Mzd = M[10], Mz0 = M[11];

        const int h = tid >> 1, k = tid & 1;
        const float fh = (float)h, fd = (float)d;
        const float bx = Mxh * fh + Mxd * fd + Mx0;

        int wlo, whi;
        if (fabsf(Mxw) > 1e-6f) {
            float rMxw = 1.0f / Mxw;
            float w1 = (47.0f - bx) * rMxw;
            float w2 = (49.0f - bx) * rMxw;
            float wmin = fminf(w1, w2), wmax = fmaxf(w1, w2);
            wlo = max((int)ceilf(wmin), 0);
            whi = min((int)floorf(wmax), SPAT - 1);
        } else {
            bool in = fabsf(bx - 48.0f) < 1.0f;
            wlo = in ? 0 : 1;
            whi = in ? SPAT - 1 : 0;
        }
        const int  qlo   = wlo >> 2, qhi = whi >> 2;
        const bool empty = (wlo > whi);
        const bool ovf   = !empty && ((qhi - qlo + 1) > KSLOT);
        if (k == 0)
            rinf[h] = empty ? 0xFFu
                : ((unsigned)qlo | ((unsigned)qhi << 8) | (ovf ? 0x10000u : 0u));

        if (!empty) {
            const float by = Myh * fh + Myd * fd + My0;
            const float bz = Mzh * fh + Mzd * fd + Mz0;
            const float* img = xin + (size_t)cc * IMG;
            if (!ovf) {
                const int myq = qlo + k;
                if (myq <= qhi)
                    sval[h * KSLOT + k] =
                        compose_chunk(myq, bx, by, bz, Mxw, Myw, Mzw, img);
                if (k == 1 && qlo + 2 <= qhi)
                    sval[h * KSLOT + 2] =
                        compose_chunk(qlo + 2, bx, by, bz, Mxw, Myw, Mzw, img);
            } else {   // pathological: write interval directly; stream skips
                f32x4* op = out + (size_t)cc * (PLANE / 4)
                                + (size_t)d * (IMG / 4) + h * 24;
                for (int q = qlo + k; q <= qhi; q += 2)
                    op[q] = compose_chunk(q, bx, by, bz, Mxw, Myw, Mzw, img);
            }
        }
    }

    __syncthreads();     // only barrier

    // ---- static per-thread chunk coordinates ----
    int hh[9], qq[9];
    #pragma unroll
    for (int it = 0; it < 9; ++it) {
        const int tl = tid + 256 * it;   // 0..2303
        hh[it] = tl / 24;
        qq[it] = tl - hh[it] * 24;
    }

    // ---- branch-free select-and-store stream (no VMEM loads) ----
    f32x4* op = out + (size_t)cc * (PLANE / 4) + (size_t)d * (IMG / 4);
    #pragma unroll
    for (int it = 0; it < 9; ++it) {
        const unsigned info = rinf[hh[it]];
        const unsigned qlo  = info & 0xFFu;
        const unsigned qhi  = (info >> 8) & 0xFFu;
        const unsigned q    = (unsigned)qq[it];
        const bool ins = (q >= qlo) & (q <= qhi);   // empty rows: qlo=255
        const bool ovf = (info & 0x10000u) != 0u;
        const int slot = min(max((int)q - (int)qlo, 0), KSLOT - 1);
        f32x4 sv = sval[hh[it] * KSLOT + slot];
        f32x4 v;
        v.x = ins ? sv.x : 0.f;
        v.y = ins ? sv.y : 0.f;
        v.z = ins ? sv.z : 0.f;
        v.w = ins ? sv.w : 0.f;
        if (!(ins && ovf))               // ovf chunks already stored by sampler
            op[tid + 256 * it] = v;
    }
}

extern "C" void kernel_launch(void* const* d_in, const int* in_sizes, int n_in,
                              void* d_out, int out_size, void* d_ws, size_t ws_size,
                              hipStream_t stream) {
    const float* x   = (const float*)d_in[0];   // [2,32,96,96] fp32
    const float* aff = (const float*)d_in[1];   // [2,2,4,4]    fp32
    float* out = (float*)d_out;                 // [2,32,96,96,96] fp32

    dim3 grid(SPAT, 64);                        // (d, cc) = 6144 blocks
    fused6_kernel<<<grid, 256, 0, stream>>>(x, aff, (f32x4*)out);
}